// Round 1
// baseline (431.014 us; speedup 1.0000x reference)
//
#include <hip/hip_runtime.h>
#include <hip/hip_bf16.h>

typedef float f32x4 __attribute__((ext_vector_type(4)));
typedef __bf16 bf16x8 __attribute__((ext_vector_type(8)));
typedef unsigned short u16x4 __attribute__((ext_vector_type(4)));
typedef unsigned short u16x8 __attribute__((ext_vector_type(8)));

__device__ __forceinline__ unsigned short f2bf(float f) {
  union { float f; unsigned u; } x; x.f = f;
  unsigned r = x.u + 0x7FFFu + ((x.u >> 16) & 1u);
  return (unsigned short)(r >> 16);
}
__device__ __forceinline__ float bf2f(unsigned short u) {
  union { unsigned u; float f; } x; x.u = ((unsigned)u) << 16;
  return x.f;
}

// ---------------- prep: W[k][n] f32 -> WT[n][k] bf16 (4 mats: q,k,v,o) ----
__global__ __launch_bounds__(256) void prep_wt(const float* __restrict__ Wq,
                                               const float* __restrict__ Wk,
                                               const float* __restrict__ Wv,
                                               const float* __restrict__ Wo,
                                               unsigned short* __restrict__ WT) {
  __shared__ unsigned short ts[64][65];
  const float* W = (blockIdx.z == 0) ? Wq : (blockIdx.z == 1) ? Wk
                   : (blockIdx.z == 2) ? Wv : Wo;
  const int t = threadIdx.x;
  const int kbase = blockIdx.y * 64;
  const int nbase = blockIdx.x * 64;
  for (int i = 0; i < 16; ++i) {
    int idx = i * 256 + t;
    int r = idx >> 6, c = idx & 63;
    ts[r][c] = f2bf(W[(size_t)(kbase + r) * 512 + nbase + c]);
  }
  __syncthreads();
  unsigned short* dst = WT + (size_t)blockIdx.z * 512 * 512;
  for (int i = 0; i < 16; ++i) {
    int idx = i * 256 + t;
    int nn = idx >> 6, kk = idx & 63;
    dst[(size_t)(nbase + nn) * 512 + kbase + kk] = ts[kk][nn];
  }
}

__global__ void prep_bias(const float* __restrict__ bq, const float* __restrict__ bk,
                          const float* __restrict__ bv, float* __restrict__ biasc) {
  int i = blockIdx.x * 256 + threadIdx.x;
  if (i < 512) biasc[i] = bq[i];
  else if (i < 1024) biasc[i] = bk[i - 512];
  else if (i < 1536) biasc[i] = bv[i - 1024];
}

// ---------------- GEMM: C[M][N] = A[M][K] @ BT[N][K]^T + bias -------------
// A: fp32 or bf16(ushort) row-major (lda), BT: bf16 [N][K] (ldb=K),
// C: bf16(ushort) or fp32 (ldc). BM=BN=128, BK=64, 256 thr, 4 waves 2x2.
__device__ __forceinline__ int lds_off(int row, int col) {
  // XOR swizzle (T2): 8-element granules spread across banks
  return (row << 6) + (col ^ ((row & 7) << 3));
}

template <typename AT, typename CT>
__global__ __launch_bounds__(256) void gemm_bf16(
    const AT* __restrict__ A, int lda,
    const unsigned short* __restrict__ BT,
    CT* __restrict__ C, int ldc,
    const float* __restrict__ bias,
    int M, int N, int K) {
  __shared__ alignas(16) unsigned short As[128 * 64];
  __shared__ alignas(16) unsigned short Bs[128 * 64];
  const int t = threadIdx.x;
  const int m0 = blockIdx.y * 128;
  const int n0 = blockIdx.x * 128;
  const int lane = t & 63;
  const int w = t >> 6;
  const int wm = w >> 1, wn = w & 1;

  f32x4 acc[4][4];
#pragma unroll
  for (int i = 0; i < 4; ++i)
#pragma unroll
    for (int j = 0; j < 4; ++j) acc[i][j] = (f32x4){0.f, 0.f, 0.f, 0.f};

  for (int k0 = 0; k0 < K; k0 += 64) {
#pragma unroll
    for (int i = 0; i < 8; ++i) {  // stage A tile 128x64
      int idx = (i * 256 + t) * 4;
      int r = idx >> 6, c = idx & 63;
      u16x4 hv;
      if constexpr (sizeof(AT) == 4) {
        f32x4 fv = *reinterpret_cast<const f32x4*>(&A[(size_t)(m0 + r) * lda + k0 + c]);
        hv[0] = f2bf(fv[0]); hv[1] = f2bf(fv[1]); hv[2] = f2bf(fv[2]); hv[3] = f2bf(fv[3]);
      } else {
        hv = *reinterpret_cast<const u16x4*>(&A[(size_t)(m0 + r) * lda + k0 + c]);
      }
      *reinterpret_cast<u16x4*>(&As[lds_off(r, c)]) = hv;
    }
#pragma unroll
    for (int i = 0; i < 8; ++i) {  // stage BT tile 128x64
      int idx = (i * 256 + t) * 4;
      int r = idx >> 6, c = idx & 63;
      u16x4 hv = *reinterpret_cast<const u16x4*>(&BT[(size_t)(n0 + r) * K + k0 + c]);
      *reinterpret_cast<u16x4*>(&Bs[lds_off(r, c)]) = hv;
    }
    __syncthreads();
#pragma unroll
    for (int kf = 0; kf < 2; ++kf) {
      bf16x8 af[4], bg[4];
#pragma unroll
      for (int mi = 0; mi < 4; ++mi)
        af[mi] = *reinterpret_cast<const bf16x8*>(
            &As[lds_off(wm * 64 + mi * 16 + (lane & 15), kf * 32 + (lane >> 4) * 8)]);
#pragma unroll
      for (int ni = 0; ni < 4; ++ni)
        bg[ni] = *reinterpret_cast<const bf16x8*>(
            &Bs[lds_off(wn * 64 + ni * 16 + (lane & 15), kf * 32 + (lane >> 4) * 8)]);
#pragma unroll
      for (int mi = 0; mi < 4; ++mi)
#pragma unroll
        for (int ni = 0; ni < 4; ++ni)
          acc[mi][ni] = __builtin_amdgcn_mfma_f32_16x16x32_bf16(af[mi], bg[ni], acc[mi][ni], 0, 0, 0);
    }
    __syncthreads();
  }

#pragma unroll
  for (int ni = 0; ni < 4; ++ni) {
    int col = n0 + wn * 64 + ni * 16 + (lane & 15);
    float bc = bias ? bias[col] : 0.0f;
#pragma unroll
    for (int mi = 0; mi < 4; ++mi) {
      int rowb = m0 + wm * 64 + mi * 16 + ((lane >> 4) << 2);
#pragma unroll
      for (int r = 0; r < 4; ++r) {
        float v = acc[mi][ni][r] + bc;
        if constexpr (sizeof(CT) == 2)
          C[(size_t)(rowb + r) * ldc + col] = (CT)f2bf(v);
        else
          C[(size_t)(rowb + r) * ldc + col] = (CT)v;
      }
    }
  }
}

// ---------------- attention: sigmoid(QK^T/8) @ V per 16-token window ------
// QKV rows [16][1536] bf16 (q|k|v). ctx overwrites the v slice (cols 1024+).
__global__ __launch_bounds__(256) void attn_kernel(unsigned short* __restrict__ QKV) {
  __shared__ alignas(16) unsigned short qs[16][1544];  // +8 pad: breaks bank aliasing
  __shared__ float ps[8][16][16];
  const int t = threadIdx.x;
  const size_t base = (size_t)blockIdx.x * 16;

  {
    int row = t >> 4;
    int cb = (t & 15) * 96;
    const unsigned short* src = QKV + (base + row) * 1536;
#pragma unroll
    for (int i = 0; i < 24; ++i) {
      int c = cb + i * 4;
      *reinterpret_cast<u16x4*>(&qs[row][c]) = *reinterpret_cast<const u16x4*>(&src[c]);
    }
  }
  __syncthreads();

  const int tq = t >> 4;   // 0..15
  const int tk = t & 15;
#pragma unroll
  for (int h = 0; h < 8; ++h) {
    float acc = 0.f;
#pragma unroll
    for (int dc = 0; dc < 64; dc += 8) {
      u16x8 q8 = *reinterpret_cast<const u16x8*>(&qs[tq][h * 64 + dc]);
      u16x8 k8 = *reinterpret_cast<const u16x8*>(&qs[tk][512 + h * 64 + dc]);
#pragma unroll
      for (int j = 0; j < 8; ++j) acc += bf2f(q8[j]) * bf2f(k8[j]);
    }
    ps[h][tq][tk] = 1.0f / (1.0f + __expf(-acc * 0.125f));
  }
  __syncthreads();

  const int row = t >> 4;
  const int cb4 = (t & 15) * 4;
  unsigned short* dst = QKV + (base + row) * 1536 + 1024;
#pragma unroll
  for (int h = 0; h < 8; ++h) {
    f32x4 acc = (f32x4){0.f, 0.f, 0.f, 0.f};
#pragma unroll
    for (int s = 0; s < 16; ++s) {
      float p = ps[h][row][s];
      u16x4 v4 = *reinterpret_cast<const u16x4*>(&qs[s][1024 + h * 64 + cb4]);
      acc[0] += p * bf2f(v4[0]); acc[1] += p * bf2f(v4[1]);
      acc[2] += p * bf2f(v4[2]); acc[3] += p * bf2f(v4[3]);
    }
    u16x4 o4;
    o4[0] = f2bf(acc[0]); o4[1] = f2bf(acc[1]); o4[2] = f2bf(acc[2]); o4[3] = f2bf(acc[3]);
    *reinterpret_cast<u16x4*>(&dst[h * 64 + cb4]) = o4;
  }
}

// --------------------------------------------------------------------------
extern "C" void kernel_launch(void* const* d_in, const int* in_sizes, int n_in,
                              void* d_out, int out_size, void* d_ws, size_t ws_size,
                              hipStream_t stream) {
  const float* x  = (const float*)d_in[0];
  const float* Wq = (const float*)d_in[1];
  const float* bq = (const float*)d_in[2];
  const float* Wk = (const float*)d_in[3];
  const float* bk = (const float*)d_in[4];
  const float* Wv = (const float*)d_in[5];
  const float* bv = (const float*)d_in[6];
  const float* Wo = (const float*)d_in[7];
  const float* bo = (const float*)d_in[8];
  float* out = (float*)d_out;

  const int M = 65536, K = 512;
  char* ws = (char*)d_ws;
  unsigned short* WT = (unsigned short*)ws;                        // [2048][512] bf16
  float* biasc = (float*)(ws + (size_t)2048 * 512 * 2);            // [1536]
  unsigned short* QKV = (unsigned short*)(ws + (size_t)2048 * 512 * 2 + 8192);
  const long long prep_bytes = (long long)2048 * 512 * 2 + 8192;

  prep_wt<<<dim3(8, 8, 4), 256, 0, stream>>>(Wq, Wk, Wv, Wo, WT);
  prep_bias<<<6, 256, 0, stream>>>(bq, bk, bv, biasc);

  // chunk rows if workspace is small (QKV chunk buffer = rows*1536*2 bytes)
  long long avail = (long long)ws_size - prep_bytes;
  int chunk_rows = 65536;
  while (chunk_rows > 128 && (long long)chunk_rows * 3072 > avail) chunk_rows >>= 1;
  int nchunks = M / chunk_rows;

  for (int c = 0; c < nchunks; ++c) {
    const size_t row0 = (size_t)c * chunk_rows;
    gemm_bf16<float, unsigned short><<<dim3(12, chunk_rows / 128), 256, 0, stream>>>(
        x + row0 * 512, 512, WT, QKV, 1536, biasc, chunk_rows, 1536, K);
    attn_kernel<<<chunk_rows / 16, 256, 0, stream>>>(QKV);
    gemm_bf16<unsigned short, float><<<dim3(4, chunk_rows / 128), 256, 0, stream>>>(
        QKV + 1024, 1536, WT + (size_t)1536 * 512, out + row0 * 512, 512, bo,
        chunk_rows, 512, K);
  }
}

// Round 2
// 360.123 us; speedup vs baseline: 1.1969x; 1.1969x over previous
//
#include <hip/hip_runtime.h>
#include <hip/hip_bf16.h>

typedef float f32x4 __attribute__((ext_vector_type(4)));
typedef __bf16 bf16x8 __attribute__((ext_vector_type(8)));
typedef unsigned short u16x4 __attribute__((ext_vector_type(4)));
typedef unsigned short u16x8 __attribute__((ext_vector_type(8)));

__device__ __forceinline__ unsigned short f2bf(float f) {
  union { float f; unsigned u; } x; x.f = f;
  unsigned r = x.u + 0x7FFFu + ((x.u >> 16) & 1u);
  return (unsigned short)(r >> 16);
}
__device__ __forceinline__ float bf2f(unsigned short u) {
  union { unsigned u; float f; } x; x.u = ((unsigned)u) << 16;
  return x.f;
}

__device__ __forceinline__ void gl16(const void* g, void* l) {
  __builtin_amdgcn_global_load_lds(
      (const __attribute__((address_space(1))) unsigned*)g,
      (__attribute__((address_space(3))) unsigned*)l, 16, 0, 0);
}

// ---------------- prep: W[k][n] f32 -> WT[n][k] bf16 (4 mats: q,k,v,o) ----
__global__ __launch_bounds__(256) void prep_wt(const float* __restrict__ Wq,
                                               const float* __restrict__ Wk,
                                               const float* __restrict__ Wv,
                                               const float* __restrict__ Wo,
                                               unsigned short* __restrict__ WT) {
  __shared__ unsigned short ts[64][65];
  const float* W = (blockIdx.z == 0) ? Wq : (blockIdx.z == 1) ? Wk
                   : (blockIdx.z == 2) ? Wv : Wo;
  const int t = threadIdx.x;
  const int kbase = blockIdx.y * 64;
  const int nbase = blockIdx.x * 64;
  for (int i = 0; i < 16; ++i) {
    int idx = i * 256 + t;
    int r = idx >> 6, c = idx & 63;
    ts[r][c] = f2bf(W[(size_t)(kbase + r) * 512 + nbase + c]);
  }
  __syncthreads();
  unsigned short* dst = WT + (size_t)blockIdx.z * 512 * 512;
  for (int i = 0; i < 16; ++i) {
    int idx = i * 256 + t;
    int nn = idx >> 6, kk = idx & 63;
    dst[(size_t)(nbase + nn) * 512 + kbase + kk] = ts[kk][nn];
  }
}

__global__ void prep_bias(const float* __restrict__ bq, const float* __restrict__ bk,
                          const float* __restrict__ bv, float* __restrict__ biasc) {
  int i = blockIdx.x * 256 + threadIdx.x;
  if (i < 512) biasc[i] = bq[i];
  else if (i < 1024) biasc[i] = bk[i - 512];
  else if (i < 1536) biasc[i] = bv[i - 1024];
}

// ---------------- convert X fp32 -> bf16 (streaming) ----------------------
__global__ __launch_bounds__(256) void convert_x(const float* __restrict__ x,
                                                 unsigned short* __restrict__ xb,
                                                 long long n8) {
  long long i = (long long)blockIdx.x * 256 + threadIdx.x;
  const long long stride = (long long)gridDim.x * 256;
  for (; i < n8; i += stride) {
    f32x4 a = *reinterpret_cast<const f32x4*>(&x[i * 8]);
    f32x4 b = *reinterpret_cast<const f32x4*>(&x[i * 8 + 4]);
    u16x8 o;
    o[0] = f2bf(a[0]); o[1] = f2bf(a[1]); o[2] = f2bf(a[2]); o[3] = f2bf(a[3]);
    o[4] = f2bf(b[0]); o[5] = f2bf(b[1]); o[6] = f2bf(b[2]); o[7] = f2bf(b[3]);
    *reinterpret_cast<u16x8*>(&xb[i * 8]) = o;
  }
}

// ---------------- GEMM (m97 structure): C = A @ BT^T + bias ---------------
// A bf16 [M][lda], BT bf16 [N][512], C bf16 or f32. BM=BN=128, BK=64,
// 256 thr = 4 waves (2x2), global_load_lds width-16 staging with
// both-sides XOR swizzle (involution cancels), XCD-aware block swizzle.
template <typename CT>
__global__ __launch_bounds__(256) void gemm_glds(
    const unsigned short* __restrict__ A, int lda,
    const unsigned short* __restrict__ BT,
    CT* __restrict__ C, int ldc,
    const float* __restrict__ bias, int NB) {
  __shared__ alignas(16) unsigned short As[128 * 64];
  __shared__ alignas(16) unsigned short Bs[128 * 64];
  const int t = threadIdx.x;
  const int lane = t & 63;
  const int w = t >> 6;
  const int wm = w >> 1, wn = w & 1;

  // XCD swizzle: consecutive wg within an XCD sweep n fastest -> A panel
  // stays in one XCD's L2. nwg is divisible by 8 by construction.
  const int nwg = gridDim.x;
  const int cpx = nwg >> 3;
  const int wg = (blockIdx.x & 7) * cpx + (blockIdx.x >> 3);
  const int n0 = (wg % NB) * 128;
  const int m0 = (wg / NB) * 128;

  const int l8 = lane >> 3, l7 = lane & 7;
  // staging: per-lane global src carries the inverse swizzle; LDS dest linear
  const unsigned short* ga = A + (size_t)(m0 + w * 32 + l8) * lda + ((l7 ^ l8) << 3);
  const unsigned short* gb = BT + (size_t)(n0 + w * 32 + l8) * 512 + ((l7 ^ l8) << 3);
  unsigned short* lA = &As[(w * 32) * 64];
  unsigned short* lB = &Bs[(w * 32) * 64];

  f32x4 acc[4][4];
#pragma unroll
  for (int i = 0; i < 4; ++i)
#pragma unroll
    for (int j = 0; j < 4; ++j) acc[i][j] = (f32x4){0.f, 0.f, 0.f, 0.f};

  for (int k0 = 0; k0 < 512; k0 += 64) {
#pragma unroll
    for (int i = 0; i < 4; ++i) {
      gl16(ga + (size_t)i * 8 * lda, lA + i * 8 * 64);
      gl16(gb + (size_t)i * 8 * 512, lB + i * 8 * 64);
    }
    ga += 64;
    gb += 64;
    __syncthreads();
#pragma unroll
    for (int kf = 0; kf < 2; ++kf) {
      bf16x8 af[4], bg[4];
#pragma unroll
      for (int mi = 0; mi < 4; ++mi) {
        int row = wm * 64 + mi * 16 + (lane & 15);
        int cb = (kf * 64 + ((lane >> 4) << 4)) ^ (l7 << 4);  // swizzled read
        af[mi] = *reinterpret_cast<const bf16x8*>(&As[row * 64 + (cb >> 1)]);
      }
#pragma unroll
      for (int ni = 0; ni < 4; ++ni) {
        int row = wn * 64 + ni * 16 + (lane & 15);
        int cb = (kf * 64 + ((lane >> 4) << 4)) ^ (l7 << 4);
        bg[ni] = *reinterpret_cast<const bf16x8*>(&Bs[row * 64 + (cb >> 1)]);
      }
#pragma unroll
      for (int mi = 0; mi < 4; ++mi)
#pragma unroll
        for (int ni = 0; ni < 4; ++ni)
          acc[mi][ni] = __builtin_amdgcn_mfma_f32_16x16x32_bf16(af[mi], bg[ni], acc[mi][ni], 0, 0, 0);
    }
    __syncthreads();
  }

#pragma unroll
  for (int ni = 0; ni < 4; ++ni) {
    int col = n0 + wn * 64 + ni * 16 + (lane & 15);
    float bc = bias ? bias[col] : 0.0f;
#pragma unroll
    for (int mi = 0; mi < 4; ++mi) {
      int rowb = m0 + wm * 64 + mi * 16 + ((lane >> 4) << 2);
#pragma unroll
      for (int r = 0; r < 4; ++r) {
        float v = acc[mi][ni][r] + bc;
        if constexpr (sizeof(CT) == 2)
          C[(size_t)(rowb + r) * ldc + col] = (CT)f2bf(v);
        else
          C[(size_t)(rowb + r) * ldc + col] = (CT)v;
      }
    }
  }
}

// ---------------- attention: sigmoid(QK^T/8) @ V per 16-token window ------
// QKV rows [16][1536] bf16 (q|k|v). ctx overwrites the v slice (cols 1024+).
__global__ __launch_bounds__(256) void attn_kernel(unsigned short* __restrict__ QKV) {
  __shared__ alignas(16) unsigned short qs[16][1544];  // +8 pad
  __shared__ unsigned short ps[8][16][16];             // probs in bf16
  const int t = threadIdx.x;
  const size_t base = (size_t)blockIdx.x * 16;

  {
    int row = t >> 4;
    int cb = (t & 15) * 96;
    const unsigned short* src = QKV + (base + row) * 1536;
#pragma unroll
    for (int i = 0; i < 24; ++i) {
      int c = cb + i * 4;
      *reinterpret_cast<u16x4*>(&qs[row][c]) = *reinterpret_cast<const u16x4*>(&src[c]);
    }
  }
  __syncthreads();

  const int tq = t >> 4;
  const int tk = t & 15;
#pragma unroll
  for (int h = 0; h < 8; ++h) {
    float acc = 0.f;
#pragma unroll
    for (int dc = 0; dc < 64; dc += 8) {
      u16x8 q8 = *reinterpret_cast<const u16x8*>(&qs[tq][h * 64 + dc]);
      u16x8 k8 = *reinterpret_cast<const u16x8*>(&qs[tk][512 + h * 64 + dc]);
#pragma unroll
      for (int j = 0; j < 8; ++j) acc += bf2f(q8[j]) * bf2f(k8[j]);
    }
    ps[h][tq][tk] = f2bf(1.0f / (1.0f + __expf(-acc * 0.125f)));
  }
  __syncthreads();

  const int row = t >> 4;
  const int cb4 = (t & 15) * 4;
  unsigned short* dst = QKV + (base + row) * 1536 + 1024;
#pragma unroll
  for (int h = 0; h < 8; ++h) {
    f32x4 acc = (f32x4){0.f, 0.f, 0.f, 0.f};
#pragma unroll
    for (int s = 0; s < 16; ++s) {
      float p = bf2f(ps[h][row][s]);
      u16x4 v4 = *reinterpret_cast<const u16x4*>(&qs[s][1024 + h * 64 + cb4]);
      acc[0] += p * bf2f(v4[0]); acc[1] += p * bf2f(v4[1]);
      acc[2] += p * bf2f(v4[2]); acc[3] += p * bf2f(v4[3]);
    }
    u16x4 o4;
    o4[0] = f2bf(acc[0]); o4[1] = f2bf(acc[1]); o4[2] = f2bf(acc[2]); o4[3] = f2bf(acc[3]);
    *reinterpret_cast<u16x4*>(&dst[h * 64 + cb4]) = o4;
  }
}

// --------------------------------------------------------------------------
extern "C" void kernel_launch(void* const* d_in, const int* in_sizes, int n_in,
                              void* d_out, int out_size, void* d_ws, size_t ws_size,
                              hipStream_t stream) {
  const float* x  = (const float*)d_in[0];
  const float* Wq = (const float*)d_in[1];
  const float* bq = (const float*)d_in[2];
  const float* Wk = (const float*)d_in[3];
  const float* bk = (const float*)d_in[4];
  const float* Wv = (const float*)d_in[5];
  const float* bv = (const float*)d_in[6];
  const float* Wo = (const float*)d_in[7];
  const float* bo = (const float*)d_in[8];
  float* out = (float*)d_out;

  const int M = 65536;
  char* ws = (char*)d_ws;
  unsigned short* WT = (unsigned short*)ws;                  // [2048][512] bf16
  float* biasc = (float*)(ws + (size_t)2048 * 512 * 2);      // [1536]
  const long long prep_bytes = (long long)2048 * 512 * 2 + 8192;

  prep_wt<<<dim3(8, 8, 4), 256, 0, stream>>>(Wq, Wk, Wv, Wo, WT);
  prep_bias<<<6, 256, 0, stream>>>(bq, bk, bv, biasc);

  // per-chunk buffers: Xb rows*512*2 B + QKV rows*1536*2 B = rows*4096 B
  long long avail = (long long)ws_size - prep_bytes;
  int chunk_rows = 65536;
  while (chunk_rows > 1024 && (long long)chunk_rows * 4096 > avail) chunk_rows >>= 1;
  const int nchunks = M / chunk_rows;

  unsigned short* Xb  = (unsigned short*)(ws + prep_bytes);
  unsigned short* QKV = Xb + (size_t)chunk_rows * 512;

  for (int c = 0; c < nchunks; ++c) {
    const size_t row0 = (size_t)c * chunk_rows;
    convert_x<<<2048, 256, 0, stream>>>(x + row0 * 512, Xb,
                                        (long long)chunk_rows * 64);
    gemm_glds<unsigned short><<<(chunk_rows / 128) * 12, 256, 0, stream>>>(
        Xb, 512, WT, QKV, 1536, biasc, 12);
    attn_kernel<<<chunk_rows / 16, 256, 0, stream>>>(QKV);
    gemm_glds<float><<<(chunk_rows / 128) * 4, 256, 0, stream>>>(
        QKV + 1024, 1536, WT + (size_t)1536 * 512, out + row0 * 512, 512, bo, 4);
  }
}

// Round 3
// 340.714 us; speedup vs baseline: 1.2650x; 1.0570x over previous
//
#include <hip/hip_runtime.h>
#include <hip/hip_bf16.h>

typedef float f32x4 __attribute__((ext_vector_type(4)));
typedef __bf16 bf16x8 __attribute__((ext_vector_type(8)));
typedef unsigned short u16x4 __attribute__((ext_vector_type(4)));
typedef unsigned short u16x8 __attribute__((ext_vector_type(8)));

__device__ __forceinline__ unsigned short f2bf(float f) {
  union { float f; unsigned u; } x; x.f = f;
  unsigned r = x.u + 0x7FFFu + ((x.u >> 16) & 1u);
  return (unsigned short)(r >> 16);
}
__device__ __forceinline__ float bf2f(unsigned short u) {
  union { unsigned u; float f; } x; x.u = ((unsigned)u) << 16;
  return x.f;
}

__device__ __forceinline__ void gl16(const void* g, void* l) {
  __builtin_amdgcn_global_load_lds(
      (const __attribute__((address_space(1))) unsigned*)g,
      (__attribute__((address_space(3))) unsigned*)l, 16, 0, 0);
}

// ---------------- prep: W[k][n] f32 -> WT[n][k] bf16 (4 mats: q,k,v,o) ----
__global__ __launch_bounds__(256) void prep_wt(const float* __restrict__ Wq,
                                               const float* __restrict__ Wk,
                                               const float* __restrict__ Wv,
                                               const float* __restrict__ Wo,
                                               unsigned short* __restrict__ WT) {
  __shared__ unsigned short ts[64][65];
  const float* W = (blockIdx.z == 0) ? Wq : (blockIdx.z == 1) ? Wk
                   : (blockIdx.z == 2) ? Wv : Wo;
  const int t = threadIdx.x;
  const int kbase = blockIdx.y * 64;
  const int nbase = blockIdx.x * 64;
  for (int i = 0; i < 16; ++i) {
    int idx = i * 256 + t;
    int r = idx >> 6, c = idx & 63;
    ts[r][c] = f2bf(W[(size_t)(kbase + r) * 512 + nbase + c]);
  }
  __syncthreads();
  unsigned short* dst = WT + (size_t)blockIdx.z * 512 * 512;
  for (int i = 0; i < 16; ++i) {
    int idx = i * 256 + t;
    int nn = idx >> 6, kk = idx & 63;
    dst[(size_t)(nbase + nn) * 512 + kbase + kk] = ts[kk][nn];
  }
}

__global__ void prep_bias(const float* __restrict__ bq, const float* __restrict__ bk,
                          const float* __restrict__ bv, float* __restrict__ biasc) {
  int i = blockIdx.x * 256 + threadIdx.x;
  if (i < 512) biasc[i] = bq[i];
  else if (i < 1024) biasc[i] = bk[i - 512];
  else if (i < 1536) biasc[i] = bv[i - 1024];
}

// ---------------- convert X fp32 -> bf16 (streaming) ----------------------
__global__ __launch_bounds__(256) void convert_x(const float* __restrict__ x,
                                                 unsigned short* __restrict__ xb,
                                                 long long n8) {
  long long i = (long long)blockIdx.x * 256 + threadIdx.x;
  const long long stride = (long long)gridDim.x * 256;
  for (; i < n8; i += stride) {
    f32x4 a = *reinterpret_cast<const f32x4*>(&x[i * 8]);
    f32x4 b = *reinterpret_cast<const f32x4*>(&x[i * 8 + 4]);
    u16x8 o;
    o[0] = f2bf(a[0]); o[1] = f2bf(a[1]); o[2] = f2bf(a[2]); o[3] = f2bf(a[3]);
    o[4] = f2bf(b[0]); o[5] = f2bf(b[1]); o[6] = f2bf(b[2]); o[7] = f2bf(b[3]);
    *reinterpret_cast<u16x8*>(&xb[i * 8]) = o;
  }
}

// ---------------- 256x256 8-phase GEMM (T2+T3+T4+T5): C = A @ BT^T + bias --
// A bf16 [M][lda], BT bf16 [N][512], K=512 fixed (8 K-tiles of BK=64).
// 512 thr = 8 waves (2m x 4n); per-wave C = 128x64. LDS 128 KiB: 2 dbuf
// x (A 256x64 + B 256x64) bf16, involution-swizzled (write src + read both
// XOR granule^(row&7)). Counted vmcnt(4) at phases 4/8 only; tail drains 0.
template <typename CT>
__global__ __launch_bounds__(512, 2) void gemm256(
    const unsigned short* __restrict__ A, int lda,
    const unsigned short* __restrict__ BT,
    CT* __restrict__ C, int ldc,
    const float* __restrict__ bias, int NB) {
  __shared__ alignas(16) unsigned short As[2][16384];
  __shared__ alignas(16) unsigned short Bs[2][16384];
  const int t = threadIdx.x;
  const int lane = t & 63;
  const int w = t >> 6;
  const int wm = w >> 2, wn = w & 3;

  // XCD-aware bijective swizzle (nwg % 8 == 0 by construction)
  const int nwg = gridDim.x;
  const int cpx = nwg >> 3;
  const int wg = (blockIdx.x & 7) * cpx + (blockIdx.x >> 3);
  const int n0 = (wg % NB) * 256;
  const int m0 = (wg / NB) * 256;

  // staging addresses: wave w covers rows w*8..w*8+7 (+64 for 2nd issue)
  const int sr = lane >> 3;                    // row within 8-row chunk
  const int sg = ((lane & 7) ^ sr) << 3;       // inverse-swizzled src granule
  const unsigned short* gA = A + (size_t)(m0 + w * 8 + sr) * lda + sg;
  const unsigned short* gB = BT + (size_t)(n0 + w * 8 + sr) * 512 + sg;
  const int lw = w * 512;                      // wave-uniform LDS base (elems)

#define STAGE_A(kt, h, b)                                                   \
  { const unsigned short* g_ = gA + (size_t)(h) * 128 * lda + (kt) * 64;    \
    unsigned short* l_ = &As[b][(h) * 8192 + lw];                           \
    gl16(g_, l_); gl16(g_ + (size_t)64 * lda, l_ + 4096); }
#define STAGE_B(kt, h, b)                                                   \
  { const unsigned short* g_ = gB + (size_t)(h) * 128 * 512 + (kt) * 64;    \
    unsigned short* l_ = &Bs[b][(h) * 8192 + lw];                           \
    gl16(g_, l_); gl16(g_ + (size_t)64 * 512, l_ + 4096); }

  const int fr = lane & 15;
  const int fg = lane >> 4;
  const int fx = lane & 7;
  auto readA = [&](int b, int mi, int kf) -> bf16x8 {
    return *reinterpret_cast<const bf16x8*>(
        &As[b][(wm * 128 + mi * 16 + fr) * 64 + ((((kf << 2) + fg) ^ fx) << 3)]);
  };
  auto readB = [&](int b, int ni, int kf) -> bf16x8 {
    return *reinterpret_cast<const bf16x8*>(
        &Bs[b][(wn * 64 + ni * 16 + fr) * 64 + ((((kf << 2) + fg) ^ fx) << 3)]);
  };

  f32x4 acc[8][4];
#pragma unroll
  for (int i = 0; i < 8; ++i)
#pragma unroll
    for (int j = 0; j < 4; ++j) acc[i][j] = (f32x4){0.f, 0.f, 0.f, 0.f};
  bf16x8 bfr[4][2];

// one phase: ds-reads | stage issue | [vmcnt] | bar | lgkm0 | MFMA*16 | bar
#define PHASE(b, q, READB, STAGES, VM)                                       \
  {                                                                          \
    bf16x8 a0_ = readA(b, 2 * (q), 0), a1_ = readA(b, 2 * (q), 1);           \
    bf16x8 a2_ = readA(b, 2 * (q) + 1, 0), a3_ = readA(b, 2 * (q) + 1, 1);   \
    if (READB) {                                                             \
      _Pragma("unroll") for (int ni = 0; ni < 4; ++ni) {                     \
        bfr[ni][0] = readB(b, ni, 0);                                        \
        bfr[ni][1] = readB(b, ni, 1);                                        \
      }                                                                      \
    }                                                                        \
    STAGES;                                                                  \
    if ((VM) == 4) asm volatile("s_waitcnt vmcnt(4)" ::: "memory");          \
    if ((VM) == 0) asm volatile("s_waitcnt vmcnt(0)" ::: "memory");          \
    __builtin_amdgcn_s_barrier();                                            \
    asm volatile("s_waitcnt lgkmcnt(0)" ::: "memory");                       \
    __builtin_amdgcn_sched_barrier(0);                                       \
    __builtin_amdgcn_s_setprio(1);                                           \
    _Pragma("unroll") for (int ni = 0; ni < 4; ++ni) {                       \
      acc[2 * (q)][ni] = __builtin_amdgcn_mfma_f32_16x16x32_bf16(            \
          a0_, bfr[ni][0], acc[2 * (q)][ni], 0, 0, 0);                       \
      acc[2 * (q)][ni] = __builtin_amdgcn_mfma_f32_16x16x32_bf16(            \
          a1_, bfr[ni][1], acc[2 * (q)][ni], 0, 0, 0);                       \
      acc[2 * (q) + 1][ni] = __builtin_amdgcn_mfma_f32_16x16x32_bf16(        \
          a2_, bfr[ni][0], acc[2 * (q) + 1][ni], 0, 0, 0);                   \
      acc[2 * (q) + 1][ni] = __builtin_amdgcn_mfma_f32_16x16x32_bf16(        \
          a3_, bfr[ni][1], acc[2 * (q) + 1][ni], 0, 0, 0);                   \
    }                                                                        \
    __builtin_amdgcn_s_setprio(0);                                           \
    __builtin_amdgcn_s_barrier();                                            \
  }

  // prologue: t0 fully + t1.B; vmcnt(4) leaves t1.B (4 loads) in flight
  STAGE_B(0, 0, 0); STAGE_B(0, 1, 0);
  STAGE_A(0, 0, 0); STAGE_A(0, 1, 0);
  STAGE_B(1, 0, 1); STAGE_B(1, 1, 1);
  asm volatile("s_waitcnt vmcnt(4)" ::: "memory");
  __builtin_amdgcn_s_barrier();

  // 4 iterations x 2 K-tiles (tile 2i -> buf0, 2i+1 -> buf1).
  // Stage legality: B-region free after its tile's first phase (B reg-held);
  // A-region free after its tile's last phase. vmcnt ledger:
  //  end-p3: outstanding <= t(2i+2).B (4)  -> tile 2i+1 landed
  //  end-p7: outstanding <= t(2i+3).B (4)  -> tile 2i+2 landed
#pragma unroll
  for (int i = 0; i < 4; ++i) {
    const bool s2 = (i < 3);  // tiles 2i+2 / 2i+3 exist?
    const int vmA = s2 ? 4 : 0;
    const int vmB = s2 ? 4 : 0;
    PHASE(0, 0, true,  { STAGE_A(2 * i + 1, 0, 1) }, -1);
    PHASE(0, 1, false, { STAGE_A(2 * i + 1, 1, 1) if (s2) STAGE_B(2 * i + 2, 0, 0) }, -1);
    PHASE(0, 2, false, { if (s2) STAGE_B(2 * i + 2, 1, 0) }, -1);
    PHASE(0, 3, false, {}, vmA);
    PHASE(1, 0, true,  { if (s2) STAGE_A(2 * i + 2, 0, 0) }, -1);
    PHASE(1, 1, false, { if (s2) STAGE_A(2 * i + 2, 1, 0) }, -1);
    PHASE(1, 2, false, { if (s2) STAGE_B(2 * i + 3, 0, 1) }, -1);
    PHASE(1, 3, false, { if (s2) STAGE_B(2 * i + 3, 1, 1) }, vmB);
  }
#undef PHASE
#undef STAGE_A
#undef STAGE_B

  // epilogue: C/D layout col=lane&15, row=(lane>>4)*4+reg (m89-verified)
#pragma unroll
  for (int ni = 0; ni < 4; ++ni) {
    int col = n0 + wn * 64 + ni * 16 + fr;
    float bc = bias[col];
#pragma unroll
    for (int mi = 0; mi < 8; ++mi) {
      int rowb = m0 + wm * 128 + mi * 16 + fg * 4;
#pragma unroll
      for (int r = 0; r < 4; ++r) {
        float v = acc[mi][ni][r] + bc;
        if constexpr (sizeof(CT) == 2)
          C[(size_t)(rowb + r) * ldc + col] = (CT)f2bf(v);
        else
          C[(size_t)(rowb + r) * ldc + col] = (CT)v;
      }
    }
  }
}

// ---------------- attention: sigmoid(QK^T/8) @ V per 16-token window ------
__global__ __launch_bounds__(256) void attn_kernel(unsigned short* __restrict__ QKV) {
  __shared__ alignas(16) unsigned short qs[16][1544];
  __shared__ unsigned short ps[8][16][16];
  const int t = threadIdx.x;
  const size_t base = (size_t)blockIdx.x * 16;

  {
    int row = t >> 4;
    int cb = (t & 15) * 96;
    const unsigned short* src = QKV + (base + row) * 1536;
#pragma unroll
    for (int i = 0; i < 24; ++i) {
      int c = cb + i * 4;
      *reinterpret_cast<u16x4*>(&qs[row][c]) = *reinterpret_cast<const u16x4*>(&src[c]);
    }
  }
  __syncthreads();

  const int tq = t >> 4;
  const int tk = t & 15;
#pragma unroll
  for (int h = 0; h < 8; ++h) {
    float acc = 0.f;
#pragma unroll
    for (int dc = 0; dc < 64; dc += 8) {
      u16x8 q8 = *reinterpret_cast<const u16x8*>(&qs[tq][h * 64 + dc]);
      u16x8 k8 = *reinterpret_cast<const u16x8*>(&qs[tk][512 + h * 64 + dc]);
#pragma unroll
      for (int j = 0; j < 8; ++j) acc += bf2f(q8[j]) * bf2f(k8[j]);
    }
    ps[h][tq][tk] = f2bf(1.0f / (1.0f + __expf(-acc * 0.125f)));
  }
  __syncthreads();

  const int row = t >> 4;
  const int cb4 = (t & 15) * 4;
  unsigned short* dst = QKV + (base + row) * 1536 + 1024;
#pragma unroll
  for (int h = 0; h < 8; ++h) {
    f32x4 acc = (f32x4){0.f, 0.f, 0.f, 0.f};
#pragma unroll
    for (int s = 0; s < 16; ++s) {
      float p = bf2f(ps[h][row][s]);
      u16x4 v4 = *reinterpret_cast<const u16x4*>(&qs[s][1024 + h * 64 + cb4]);
      acc[0] += p * bf2f(v4[0]); acc[1] += p * bf2f(v4[1]);
      acc[2] += p * bf2f(v4[2]); acc[3] += p * bf2f(v4[3]);
    }
    u16x4 o4;
    o4[0] = f2bf(acc[0]); o4[1] = f2bf(acc[1]); o4[2] = f2bf(acc[2]); o4[3] = f2bf(acc[3]);
    *reinterpret_cast<u16x4*>(&dst[h * 64 + cb4]) = o4;
  }
}

// --------------------------------------------------------------------------
extern "C" void kernel_launch(void* const* d_in, const int* in_sizes, int n_in,
                              void* d_out, int out_size, void* d_ws, size_t ws_size,
                              hipStream_t stream) {
  const float* x  = (const float*)d_in[0];
  const float* Wq = (const float*)d_in[1];
  const float* bq = (const float*)d_in[2];
  const float* Wk = (const float*)d_in[3];
  const float* bk = (const float*)d_in[4];
  const float* Wv = (const float*)d_in[5];
  const float* bv = (const float*)d_in[6];
  const float* Wo = (const float*)d_in[7];
  const float* bo = (const float*)d_in[8];
  float* out = (float*)d_out;

  const int M = 65536;
  char* ws = (char*)d_ws;
  unsigned short* WT = (unsigned short*)ws;                  // [2048][512] bf16
  float* biasc = (float*)(ws + (size_t)2048 * 512 * 2);      // [1536]
  const long long prep_bytes = (long long)2048 * 512 * 2 + 8192;

  prep_wt<<<dim3(8, 8, 4), 256, 0, stream>>>(Wq, Wk, Wv, Wo, WT);
  prep_bias<<<6, 256, 0, stream>>>(bq, bk, bv, biasc);

  // per-chunk: Xb rows*512*2 B + QKV rows*1536*2 B = rows*4096 B
  long long avail = (long long)ws_size - prep_bytes;
  int chunk_rows = 65536;
  while (chunk_rows > 2048 && (long long)chunk_rows * 4096 > avail) chunk_rows >>= 1;
  const int nchunks = M / chunk_rows;

  unsigned short* Xb  = (unsigned short*)(ws + prep_bytes);
  unsigned short* QKV = Xb + (size_t)chunk_rows * 512;

  for (int c = 0; c < nchunks; ++c) {
    const size_t row0 = (size_t)c * chunk_rows;
    const int mt = chunk_rows / 256;
    convert_x<<<2048, 256, 0, stream>>>(x + row0 * 512, Xb,
                                        (long long)chunk_rows * 64);
    gemm256<unsigned short><<<mt * 6, 512, 0, stream>>>(
        Xb, 512, WT, QKV, 1536, biasc, 6);
    attn_kernel<<<chunk_rows / 16, 256, 0, stream>>>(QKV);
    gemm256<float><<<mt * 2, 512, 0, stream>>>(
        QKV + 1024, 1536, WT + (size_t)1536 * 512, out + row0 * 512, 512, bo, 2);
  }
}

// Round 4
// 302.704 us; speedup vs baseline: 1.4239x; 1.1256x over previous
//
#include <hip/hip_runtime.h>
#include <hip/hip_bf16.h>

typedef float f32x4 __attribute__((ext_vector_type(4)));
typedef __bf16 bf16x8 __attribute__((ext_vector_type(8)));
typedef unsigned short u16x4 __attribute__((ext_vector_type(4)));
typedef unsigned short u16x8 __attribute__((ext_vector_type(8)));

__device__ __forceinline__ unsigned short f2bf(float f) {
  union { float f; unsigned u; } x; x.f = f;
  unsigned r = x.u + 0x7FFFu + ((x.u >> 16) & 1u);
  return (unsigned short)(r >> 16);
}
__device__ __forceinline__ float bf2f(unsigned short u) {
  union { unsigned u; float f; } x; x.u = ((unsigned)u) << 16;
  return x.f;
}

__device__ __forceinline__ void gl16(const void* g, void* l) {
  __builtin_amdgcn_global_load_lds(
      (const __attribute__((address_space(1))) unsigned*)g,
      (__attribute__((address_space(3))) unsigned*)l, 16, 0, 0);
}

// ---------------- prep: W[k][n] f32 -> WT[n][k] bf16 (4 mats: q,k,v,o) ----
__global__ __launch_bounds__(256) void prep_wt(const float* __restrict__ Wq,
                                               const float* __restrict__ Wk,
                                               const float* __restrict__ Wv,
                                               const float* __restrict__ Wo,
                                               unsigned short* __restrict__ WT) {
  __shared__ unsigned short ts[64][65];
  const float* W = (blockIdx.z == 0) ? Wq : (blockIdx.z == 1) ? Wk
                   : (blockIdx.z == 2) ? Wv : Wo;
  const int t = threadIdx.x;
  const int kbase = blockIdx.y * 64;
  const int nbase = blockIdx.x * 64;
  for (int i = 0; i < 16; ++i) {
    int idx = i * 256 + t;
    int r = idx >> 6, c = idx & 63;
    ts[r][c] = f2bf(W[(size_t)(kbase + r) * 512 + nbase + c]);
  }
  __syncthreads();
  unsigned short* dst = WT + (size_t)blockIdx.z * 512 * 512;
  for (int i = 0; i < 16; ++i) {
    int idx = i * 256 + t;
    int nn = idx >> 6, kk = idx & 63;
    dst[(size_t)(nbase + nn) * 512 + kbase + kk] = ts[kk][nn];
  }
}

__global__ void prep_bias(const float* __restrict__ bq, const float* __restrict__ bk,
                          const float* __restrict__ bv, float* __restrict__ biasc) {
  int i = blockIdx.x * 256 + threadIdx.x;
  if (i < 512) biasc[i] = bq[i];
  else if (i < 1024) biasc[i] = bk[i - 512];
  else if (i < 1536) biasc[i] = bv[i - 1024];
}

// ---------------- convert X fp32 -> bf16 (streaming) ----------------------
__global__ __launch_bounds__(256) void convert_x(const float* __restrict__ x,
                                                 unsigned short* __restrict__ xb,
                                                 long long n8) {
  long long i = (long long)blockIdx.x * 256 + threadIdx.x;
  const long long stride = (long long)gridDim.x * 256;
  for (; i < n8; i += stride) {
    f32x4 a = *reinterpret_cast<const f32x4*>(&x[i * 8]);
    f32x4 b = *reinterpret_cast<const f32x4*>(&x[i * 8 + 4]);
    u16x8 o;
    o[0] = f2bf(a[0]); o[1] = f2bf(a[1]); o[2] = f2bf(a[2]); o[3] = f2bf(a[3]);
    o[4] = f2bf(b[0]); o[5] = f2bf(b[1]); o[6] = f2bf(b[2]); o[7] = f2bf(b[3]);
    *reinterpret_cast<u16x8*>(&xb[i * 8]) = o;
  }
}

// ---------------- 256x256 8-phase GEMM: C = A @ BT^T + bias ---------------
// A bf16 [M][lda], BT bf16 [N][512], K=512 (8 K-tiles of BK=64).
// 512 thr = 8 waves (2m x 4n). LDS pool 129 KiB: K-loop = 2dbuf x (A+B)
// 256x64 bf16 swizzled; epilogue reuses pool for coalesced C staging.
template <typename CT>
__global__ __launch_bounds__(512, 2) void gemm256(
    const unsigned short* __restrict__ A, int lda,
    const unsigned short* __restrict__ BT,
    CT* __restrict__ C, int ldc,
    const float* __restrict__ bias, int NB) {
  __shared__ alignas(16) unsigned short pool[66048];  // 132096 B
  const int t = threadIdx.x;
  const int lane = t & 63;
  const int w = t >> 6;
  const int wm = w >> 2, wn = w & 3;

  // XCD-aware bijective swizzle (nwg % 8 == 0 by construction)
  const int nwg = gridDim.x;
  const int cpx = nwg >> 3;
  const int wg = (blockIdx.x & 7) * cpx + (blockIdx.x >> 3);
  const int n0 = (wg % NB) * 256;
  const int m0 = (wg / NB) * 256;

  // staging addresses: wave w covers rows w*8..w*8+7 (+64 for 2nd issue)
  const int sr = lane >> 3;
  const int sg = ((lane & 7) ^ sr) << 3;       // inverse-swizzled src granule
  const unsigned short* gA = A + (size_t)(m0 + w * 8 + sr) * lda + sg;
  const unsigned short* gB = BT + (size_t)(n0 + w * 8 + sr) * 512 + sg;
  const int lw = w * 512;

#define STAGE_A(kt, h, b)                                                   \
  { const unsigned short* g_ = gA + (size_t)(h) * 128 * lda + (kt) * 64;    \
    unsigned short* l_ = &pool[(b) * 16384 + (h) * 8192 + lw];              \
    gl16(g_, l_); gl16(g_ + (size_t)64 * lda, l_ + 4096); }
#define STAGE_B(kt, h, b)                                                   \
  { const unsigned short* g_ = gB + (size_t)(h) * 128 * 512 + (kt) * 64;    \
    unsigned short* l_ = &pool[32768 + (b) * 16384 + (h) * 8192 + lw];      \
    gl16(g_, l_); gl16(g_ + (size_t)64 * 512, l_ + 4096); }

  const int fr = lane & 15;
  const int fg = lane >> 4;
  const int fx = lane & 7;
  auto readA = [&](int b, int mi, int kf) -> bf16x8 {
    return *reinterpret_cast<const bf16x8*>(
        &pool[(b) * 16384 + (wm * 128 + mi * 16 + fr) * 64 +
              ((((kf << 2) + fg) ^ fx) << 3)]);
  };
  auto readB = [&](int b, int ni, int kf) -> bf16x8 {
    return *reinterpret_cast<const bf16x8*>(
        &pool[32768 + (b) * 16384 + (wn * 64 + ni * 16 + fr) * 64 +
              ((((kf << 2) + fg) ^ fx) << 3)]);
  };

  f32x4 acc[8][4];
#pragma unroll
  for (int i = 0; i < 8; ++i)
#pragma unroll
    for (int j = 0; j < 4; ++j) acc[i][j] = (f32x4){0.f, 0.f, 0.f, 0.f};
  bf16x8 bfr[4][2];

// one phase: ds-reads | stage issue | [vmcnt] | bar | lgkm0 | MFMA*16 | bar
// MFMA order: all kf=0 first, then kf=1 -> dependent pairs 8 apart.
#define PHASE(b, q, READB, STAGES, VM)                                       \
  {                                                                          \
    bf16x8 a0_ = readA(b, 2 * (q), 0), a1_ = readA(b, 2 * (q), 1);           \
    bf16x8 a2_ = readA(b, 2 * (q) + 1, 0), a3_ = readA(b, 2 * (q) + 1, 1);   \
    if (READB) {                                                             \
      _Pragma("unroll") for (int ni = 0; ni < 4; ++ni) {                     \
        bfr[ni][0] = readB(b, ni, 0);                                        \
        bfr[ni][1] = readB(b, ni, 1);                                        \
      }                                                                      \
    }                                                                        \
    STAGES;                                                                  \
    if ((VM) == 4) asm volatile("s_waitcnt vmcnt(4)" ::: "memory");          \
    if ((VM) == 0) asm volatile("s_waitcnt vmcnt(0)" ::: "memory");          \
    __builtin_amdgcn_s_barrier();                                            \
    asm volatile("s_waitcnt lgkmcnt(0)" ::: "memory");                       \
    __builtin_amdgcn_sched_barrier(0);                                       \
    __builtin_amdgcn_s_setprio(1);                                           \
    _Pragma("unroll") for (int ni = 0; ni < 4; ++ni) {                       \
      acc[2 * (q)][ni] = __builtin_amdgcn_mfma_f32_16x16x32_bf16(            \
          a0_, bfr[ni][0], acc[2 * (q)][ni], 0, 0, 0);                       \
      acc[2 * (q) + 1][ni] = __builtin_amdgcn_mfma_f32_16x16x32_bf16(        \
          a2_, bfr[ni][0], acc[2 * (q) + 1][ni], 0, 0, 0);                   \
    }                                                                        \
    _Pragma("unroll") for (int ni = 0; ni < 4; ++ni) {                       \
      acc[2 * (q)][ni] = __builtin_amdgcn_mfma_f32_16x16x32_bf16(            \
          a1_, bfr[ni][1], acc[2 * (q)][ni], 0, 0, 0);                       \
      acc[2 * (q) + 1][ni] = __builtin_amdgcn_mfma_f32_16x16x32_bf16(        \
          a3_, bfr[ni][1], acc[2 * (q) + 1][ni], 0, 0, 0);                   \
    }                                                                        \
    __builtin_amdgcn_s_setprio(0);                                           \
    __builtin_amdgcn_s_barrier();                                            \
  }

  // prologue: t0 fully + t1.B; vmcnt(4) leaves t1.B (4 loads) in flight
  STAGE_B(0, 0, 0); STAGE_B(0, 1, 0);
  STAGE_A(0, 0, 0); STAGE_A(0, 1, 0);
  STAGE_B(1, 0, 1); STAGE_B(1, 1, 1);
  asm volatile("s_waitcnt vmcnt(4)" ::: "memory");
  __builtin_amdgcn_s_barrier();

  // 4 iterations x 2 K-tiles (tile 2i -> buf0, 2i+1 -> buf1).
#pragma unroll
  for (int i = 0; i < 4; ++i) {
    const bool s2 = (i < 3);
    const int vmA = s2 ? 4 : 0;
    const int vmB = s2 ? 4 : 0;
    PHASE(0, 0, true,  { STAGE_A(2 * i + 1, 0, 1) }, -1);
    PHASE(0, 1, false, { STAGE_A(2 * i + 1, 1, 1) if (s2) STAGE_B(2 * i + 2, 0, 0) }, -1);
    PHASE(0, 2, false, { if (s2) STAGE_B(2 * i + 2, 1, 0) }, -1);
    PHASE(0, 3, false, {}, vmA);
    PHASE(1, 0, true,  { if (s2) STAGE_A(2 * i + 2, 0, 0) }, -1);
    PHASE(1, 1, false, { if (s2) STAGE_A(2 * i + 2, 1, 0) }, -1);
    PHASE(1, 2, false, { if (s2) STAGE_B(2 * i + 3, 0, 1) }, -1);
    PHASE(1, 3, false, { if (s2) STAGE_B(2 * i + 3, 1, 1) }, vmB);
  }
#undef PHASE
#undef STAGE_A
#undef STAGE_B

  // ---- coalesced epilogue via LDS staging (C/D layout m89-verified) ----
  __syncthreads();
  if constexpr (sizeof(CT) == 2) {
    // bf16: full 256x256 tile, stride 258 (pad breaks bank aliasing)
#pragma unroll
    for (int ni = 0; ni < 4; ++ni) {
      int cl = wn * 64 + ni * 16 + fr;
      float bc = bias[n0 + cl];
#pragma unroll
      for (int mi = 0; mi < 8; ++mi) {
        int rl = wm * 128 + mi * 16 + fg * 4;
#pragma unroll
        for (int r = 0; r < 4; ++r)
          pool[(rl + r) * 258 + cl] = f2bf(acc[mi][ni][r] + bc);
      }
    }
    __syncthreads();
#pragma unroll
    for (int it = 0; it < 16; ++it) {
      int idx = it * 512 + t;
      int row = idx >> 5, c8 = idx & 31;
      u16x8 v = *reinterpret_cast<const u16x8*>(&pool[row * 258 + c8 * 8]);
      *reinterpret_cast<u16x8*>(&C[(size_t)(m0 + row) * ldc + n0 + c8 * 8]) = v;
    }
  } else {
    // fp32: two 128-row halves through the same pool
    float* stf = reinterpret_cast<float*>(pool);
#pragma unroll
    for (int h = 0; h < 2; ++h) {
      if (wm == h) {
#pragma unroll
        for (int ni = 0; ni < 4; ++ni) {
          int cl = wn * 64 + ni * 16 + fr;
          float bc = bias[n0 + cl];
#pragma unroll
          for (int mi = 0; mi < 8; ++mi) {
            int rl = mi * 16 + fg * 4;
#pragma unroll
            for (int r = 0; r < 4; ++r)
              stf[(rl + r) * 258 + cl] = acc[mi][ni][r] + bc;
          }
        }
      }
      __syncthreads();
#pragma unroll
      for (int it = 0; it < 16; ++it) {
        int idx = it * 512 + t;
        int row = idx >> 6, c4 = idx & 63;
        f32x4 v = *reinterpret_cast<const f32x4*>(&stf[row * 258 + c4 * 4]);
        *reinterpret_cast<f32x4*>(
            &C[(size_t)(m0 + h * 128 + row) * ldc + n0 + c4 * 4]) = v;
      }
      __syncthreads();
    }
  }
}

// ---------------- attention: sigmoid(QK^T/8) @ V per 16-token window ------
__global__ __launch_bounds__(256) void attn_kernel(unsigned short* __restrict__ QKV) {
  __shared__ alignas(16) unsigned short qs[16][1544];
  __shared__ unsigned short ps[8][16][16];
  const int t = threadIdx.x;
  const size_t base = (size_t)blockIdx.x * 16;

  {
    int row = t >> 4;
    int cb = (t & 15) * 96;
    const unsigned short* src = QKV + (base + row) * 1536;
#pragma unroll
    for (int i = 0; i < 24; ++i) {
      int c = cb + i * 4;
      *reinterpret_cast<u16x4*>(&qs[row][c]) = *reinterpret_cast<const u16x4*>(&src[c]);
    }
  }
  __syncthreads();

  const int tq = t >> 4;
  const int tk = t & 15;
#pragma unroll
  for (int h = 0; h < 8; ++h) {
    float acc = 0.f;
#pragma unroll
    for (int dc = 0; dc < 64; dc += 8) {
      u16x8 q8 = *reinterpret_cast<const u16x8*>(&qs[tq][h * 64 + dc]);
      u16x8 k8 = *reinterpret_cast<const u16x8*>(&qs[tk][512 + h * 64 + dc]);
#pragma unroll
      for (int j = 0; j < 8; ++j) acc += bf2f(q8[j]) * bf2f(k8[j]);
    }
    ps[h][tq][tk] = f2bf(1.0f / (1.0f + __expf(-acc * 0.125f)));
  }
  __syncthreads();

  const int row = t >> 4;
  const int cb4 = (t & 15) * 4;
  unsigned short* dst = QKV + (base + row) * 1536 + 1024;
#pragma unroll
  for (int h = 0; h < 8; ++h) {
    f32x4 acc = (f32x4){0.f, 0.f, 0.f, 0.f};
#pragma unroll
    for (int s = 0; s < 16; ++s) {
      float p = bf2f(ps[h][row][s]);
      u16x4 v4 = *reinterpret_cast<const u16x4*>(&qs[s][1024 + h * 64 + cb4]);
      acc[0] += p * bf2f(v4[0]); acc[1] += p * bf2f(v4[1]);
      acc[2] += p * bf2f(v4[2]); acc[3] += p * bf2f(v4[3]);
    }
    u16x4 o4;
    o4[0] = f2bf(acc[0]); o4[1] = f2bf(acc[1]); o4[2] = f2bf(acc[2]); o4[3] = f2bf(acc[3]);
    *reinterpret_cast<u16x4*>(&dst[h * 64 + cb4]) = o4;
  }
}

// --------------------------------------------------------------------------
extern "C" void kernel_launch(void* const* d_in, const int* in_sizes, int n_in,
                              void* d_out, int out_size, void* d_ws, size_t ws_size,
                              hipStream_t stream) {
  const float* x  = (const float*)d_in[0];
  const float* Wq = (const float*)d_in[1];
  const float* bq = (const float*)d_in[2];
  const float* Wk = (const float*)d_in[3];
  const float* bk = (const float*)d_in[4];
  const float* Wv = (const float*)d_in[5];
  const float* bv = (const float*)d_in[6];
  const float* Wo = (const float*)d_in[7];
  const float* bo = (const float*)d_in[8];
  float* out = (float*)d_out;

  const int M = 65536;
  char* ws = (char*)d_ws;
  unsigned short* WT = (unsigned short*)ws;                  // [2048][512] bf16
  float* biasc = (float*)(ws + (size_t)2048 * 512 * 2);      // [1536]
  const long long prep_bytes = (long long)2048 * 512 * 2 + 8192;

  prep_wt<<<dim3(8, 8, 4), 256, 0, stream>>>(Wq, Wk, Wv, Wo, WT);
  prep_bias<<<6, 256, 0, stream>>>(bq, bk, bv, biasc);

  // per-chunk: Xb rows*512*2 B + QKV rows*1536*2 B = rows*4096 B
  long long avail = (long long)ws_size - prep_bytes;
  int chunk_rows = 65536;
  while (chunk_rows > 2048 && (long long)chunk_rows * 4096 > avail) chunk_rows >>= 1;
  const int nchunks = M / chunk_rows;

  unsigned short* Xb  = (unsigned short*)(ws + prep_bytes);
  unsigned short* QKV = Xb + (size_t)chunk_rows * 512;

  for (int c = 0; c < nchunks; ++c) {
    const size_t row0 = (size_t)c * chunk_rows;
    const int mt = chunk_rows / 256;
    convert_x<<<2048, 256, 0, stream>>>(x + row0 * 512, Xb,
                                        (long long)chunk_rows * 64);
    gemm256<unsigned short><<<mt * 6, 512, 0, stream>>>(
        Xb, 512, WT, QKV, 1536, biasc, 6);
    attn_kernel<<<chunk_rows / 16, 256, 0, stream>>>(QKV);
    gemm256<float><<<mt * 2, 512, 0, stream>>>(
        QKV + 1024, 1536, WT + (size_t)1536 * 512, out + row0 * 512, 512, bo, 2);
  }
}